// Round 9
// baseline (2363.799 us; speedup 1.0000x reference)
//
#include <hip/hip_runtime.h>
#include <math.h>

#define D 768
#define NPROTO 20
#define NCLS 13
#define D4 (D / 4)      // 192 float4 per row
#define NCHUNK 12       // 16 lanes/row, one float4 each -> 12 chunks

__device__ __forceinline__ float dot4f(const float4 a, const float4 b) {
    return a.x * b.x + a.y * b.y + a.z * b.z + a.w * b.w;
}

template <int CTRL>
__device__ __forceinline__ float dpp_mov(float v) {
    return __int_as_float(__builtin_amdgcn_update_dpp(
        0, __float_as_int(v), CTRL, 0xF, 0xF, true));
}

// 16-lane butterfly, bit-identical pairing to __shfl_xor s=1,2,4,8,
// entirely on the VALU pipe (DPP). Verified on HW in round 8 (absmax 0.0).
// row_shr:N => lane i <- i-N ; row_shl:N => lane i <- i+N.
__device__ __forceinline__ float red16(float v, bool hi4) {
    v += dpp_mov<0xB1>(v);                 // quad_perm [1,0,3,2]  == xor 1
    v += dpp_mov<0x4E>(v);                 // quad_perm [2,3,0,1]  == xor 2
    const float up   = dpp_mov<0x114>(v);  // row_shr:4 : lane i <- i-4
    const float down = dpp_mov<0x104>(v);  // row_shl:4 : lane i <- i+4
    v += hi4 ? up : down;                  // exact partner lane^4
    v += dpp_mov<0x128>(v);                // row_ror:8 == xor 8 within 16
    return v;
}

// ws layout (floats): [0, 15360) protos_norm [20][768]; [15360, 15620) logits [20][13]

// One block per prototype. Numerics identical to rounds 1-8 (passed) prep.
__global__ __launch_bounds__(256) void proto_prep(
    const float* __restrict__ prototypes,
    const int* __restrict__ role_id,
    const float* __restrict__ W,
    const float* __restrict__ bvec,
    float* __restrict__ ws)
{
    const int p = blockIdx.x;            // 0..19
    const int tid = threadIdx.x;
    const int wave = tid >> 6;
    const int lane = tid & 63;

    const float4* src = reinterpret_cast<const float4*>(
        prototypes + ((size_t)role_id[0] * NPROTO + p) * D);
    float4 v[3];
    #pragma unroll
    for (int j = 0; j < 3; ++j) v[j] = src[lane + 64 * j];

    float ss = 0.f;
    #pragma unroll
    for (int j = 0; j < 3; ++j) ss += dot4f(v[j], v[j]);
    #pragma unroll
    for (int s = 1; s < 64; s <<= 1) ss += __shfl_xor(ss, s, 64);
    const float nrm = fmaxf(sqrtf(ss), 1e-12f);

    float4 nv[3];
    #pragma unroll
    for (int j = 0; j < 3; ++j) {
        nv[j].x = v[j].x / nrm; nv[j].y = v[j].y / nrm;
        nv[j].z = v[j].z / nrm; nv[j].w = v[j].w / nrm;
    }
    if (wave == 0) {
        float4* dst = reinterpret_cast<float4*>(ws + (size_t)p * D);
        #pragma unroll
        for (int j = 0; j < 3; ++j) dst[lane + 64 * j] = nv[j];
    }

    for (int r = wave; r < NCLS; r += 4) {
        const float4* wr = reinterpret_cast<const float4*>(W + (size_t)r * D);
        float a = 0.f;
        #pragma unroll
        for (int j = 0; j < 3; ++j) a += dot4f(nv[j], wr[lane + 64 * j]);
        #pragma unroll
        for (int s = 1; s < 64; s <<= 1) a += __shfl_xor(a, s, 64);
        if (lane == 0) ws[NPROTO * D + p * NCLS + r] = a + bvec[r];
    }
}

// Zero-LDS main kernel: protos read per-chunk from global ws (61 KB working
// set, L1/L2-resident, broadcast across the wave's 4 groups). 16 lanes/row,
// 2 rows/group -> 32 rows per 256-thr block. No launch_bounds cap -> no
// spill; occupancy set by VGPRs (~3 waves/SIMD) over 4096 blocks.
__global__ void proto_main(
    const float* __restrict__ x,
    const float* __restrict__ ws,
    float* __restrict__ out_min,
    float* __restrict__ out_pred)
{
    const int tid = threadIdx.x;
    const int wave = tid >> 6;      // 0..3
    const int lane = tid & 63;
    const int g   = lane >> 4;      // group within wave (2 rows each)
    const int sub = lane & 15;      // float4 slot within a 16-float4 chunk
    const bool hi4 = (lane & 4) != 0;
    const int row0 = blockIdx.x * 32 + wave * 8 + g * 2;

    const float4* xr0 = reinterpret_cast<const float4*>(x + (size_t)(row0 + 0) * D) + sub;
    const float4* xr1 = reinterpret_cast<const float4*>(x + (size_t)(row0 + 1) * D) + sub;
    const float4* gp  = reinterpret_cast<const float4*>(ws) + sub;   // protos_norm

    float acc[NPROTO][2];
    #pragma unroll
    for (int p = 0; p < NPROTO; ++p) { acc[p][0] = 0.f; acc[p][1] = 0.f; }
    float ssx[2] = {0.f, 0.f};

    float4 xa[2], xn[2];            // depth-1 ping-pong prefetch
    xa[0] = xr0[0]; xa[1] = xr1[0];

    #pragma unroll
    for (int j = 0; j < NCHUNK; ++j) {
        if (j + 1 < NCHUNK) {
            xn[0] = xr0[16 * (j + 1)];
            xn[1] = xr1[16 * (j + 1)];
        }
        const float4* pp = gp + 16 * j;
        #pragma unroll
        for (int p = 0; p < NPROTO; ++p) {
            const float4 pv = pp[p * D4];
            acc[p][0] += dot4f(xa[0], pv);
            acc[p][1] += dot4f(xa[1], pv);
        }
        ssx[0] += dot4f(xa[0], xa[0]);
        ssx[1] += dot4f(xa[1], xa[1]);
        if (j + 1 < NCHUNK) { xa[0] = xn[0]; xa[1] = xn[1]; }
    }

    #pragma unroll
    for (int r = 0; r < 2; ++r) {
        const float ss = red16(ssx[r], hi4);
        const float inv = 1.0f / fmaxf(sqrtf(ss), 1e-12f);

        // np-order scan in dist space (strict > keeps first index on ties)
        float best = 0.f; int bidx = 0;
        #pragma unroll
        for (int p = 0; p < NPROTO; ++p) {
            const float sim = red16(acc[p][r], hi4) * inv;
            const float u = expf(sim) / 10.0f;
            const float dcur = 1.0f / (1.0f + u);
            if (p == 0) best = dcur;
            else if (dcur > best) { best = dcur; bidx = p; }
        }

        const int row = row0 + r;
        if (sub == 0) out_min[row] = best;
        if (sub < NCLS)
            out_pred[(size_t)row * NCLS + sub] = ws[NPROTO * D + bidx * NCLS + sub];
    }
}

extern "C" void kernel_launch(void* const* d_in, const int* in_sizes, int n_in,
                              void* d_out, int out_size, void* d_ws, size_t ws_size,
                              hipStream_t stream) {
    const float* x          = (const float*)d_in[0];   // [B, 768]
    const int*   role_id    = (const int*)d_in[1];     // scalar
    const float* prototypes = (const float*)d_in[2];   // [260, 768]
    const float* W          = (const float*)d_in[3];   // [13, 768]
    const float* b          = (const float*)d_in[4];   // [13]
    float* out = (float*)d_out;
    float* ws  = (float*)d_ws;

    const int B = in_sizes[0] / D;                     // 131072

    proto_prep<<<NPROTO, 256, 0, stream>>>(prototypes, role_id, W, b, ws);
    proto_main<<<B / 32, 256, 0, stream>>>(x, ws, out, out + B);
}

// Round 10
// 1675.946 us; speedup vs baseline: 1.4104x; 1.4104x over previous
//
#include <hip/hip_runtime.h>
#include <math.h>

#define D 768
#define NPROTO 20
#define NCLS 13
#define D4 (D / 4)      // 192 float4 per row
#define NCHUNK 12       // 16 lanes/row, one float4 each -> 12 chunks

__device__ __forceinline__ float dot4f(const float4 a, const float4 b) {
    return a.x * b.x + a.y * b.y + a.z * b.z + a.w * b.w;
}

template <int CTRL>
__device__ __forceinline__ float dpp_mov(float v) {
    return __int_as_float(__builtin_amdgcn_update_dpp(
        0, __float_as_int(v), CTRL, 0xF, 0xF, true));
}

// 16-lane butterfly, bit-identical pairing to __shfl_xor s=1,2,4,8,
// entirely on the VALU pipe (DPP). Verified on HW in rounds 8/9 (absmax 0.0).
// row_shr:N => lane i <- i-N ; row_shl:N => lane i <- i+N.
__device__ __forceinline__ float red16(float v, bool hi4) {
    v += dpp_mov<0xB1>(v);                 // quad_perm [1,0,3,2]  == xor 1
    v += dpp_mov<0x4E>(v);                 // quad_perm [2,3,0,1]  == xor 2
    const float up   = dpp_mov<0x114>(v);  // row_shr:4 : lane i <- i-4
    const float down = dpp_mov<0x104>(v);  // row_shl:4 : lane i <- i+4
    v += hi4 ? up : down;                  // exact partner lane^4
    v += dpp_mov<0x128>(v);                // row_ror:8 == xor 8 within 16
    return v;
}

// ws layout (floats): [0, 15360) protos_norm [20][768]; [15360, 15620) logits [20][13]

// One block per prototype. Numerics identical to rounds 1-9 (passed) prep.
__global__ __launch_bounds__(256) void proto_prep(
    const float* __restrict__ prototypes,
    const int* __restrict__ role_id,
    const float* __restrict__ W,
    const float* __restrict__ bvec,
    float* __restrict__ ws)
{
    const int p = blockIdx.x;            // 0..19
    const int tid = threadIdx.x;
    const int wave = tid >> 6;
    const int lane = tid & 63;

    const float4* src = reinterpret_cast<const float4*>(
        prototypes + ((size_t)role_id[0] * NPROTO + p) * D);
    float4 v[3];
    #pragma unroll
    for (int j = 0; j < 3; ++j) v[j] = src[lane + 64 * j];

    float ss = 0.f;
    #pragma unroll
    for (int j = 0; j < 3; ++j) ss += dot4f(v[j], v[j]);
    #pragma unroll
    for (int s = 1; s < 64; s <<= 1) ss += __shfl_xor(ss, s, 64);
    const float nrm = fmaxf(sqrtf(ss), 1e-12f);

    float4 nv[3];
    #pragma unroll
    for (int j = 0; j < 3; ++j) {
        nv[j].x = v[j].x / nrm; nv[j].y = v[j].y / nrm;
        nv[j].z = v[j].z / nrm; nv[j].w = v[j].w / nrm;
    }
    if (wave == 0) {
        float4* dst = reinterpret_cast<float4*>(ws + (size_t)p * D);
        #pragma unroll
        for (int j = 0; j < 3; ++j) dst[lane + 64 * j] = nv[j];
    }

    for (int r = wave; r < NCLS; r += 4) {
        const float4* wr = reinterpret_cast<const float4*>(W + (size_t)r * D);
        float a = 0.f;
        #pragma unroll
        for (int j = 0; j < 3; ++j) a += dot4f(nv[j], wr[lane + 64 * j]);
        #pragma unroll
        for (int s = 1; s < 64; s <<= 1) a += __shfl_xor(a, s, 64);
        if (lane == 0) ws[NPROTO * D + p * NCLS + r] = a + bvec[r];
    }
}

// Zero-LDS main kernel: protos read per-chunk from global ws (61 KB working
// set, L1/L2-resident, broadcast across the wave's 4 groups). 16 lanes/row,
// 2 rows/group -> 32 rows per 256-thr block, 4096 blocks.
// __launch_bounds__(256, 1): VGPR budget 512 -> compiler allocates its
// natural ~170, NO spill (r4/r5/r8/r9 all died to forced caps: budget
// empirically = 256 / second-arg, and no-attribute default = 64).
__global__ __launch_bounds__(256, 1) void proto_main(
    const float* __restrict__ x,
    const float* __restrict__ ws,
    float* __restrict__ out_min,
    float* __restrict__ out_pred)
{
    const int tid = threadIdx.x;
    const int wave = tid >> 6;      // 0..3
    const int lane = tid & 63;
    const int g   = lane >> 4;      // group within wave (2 rows each)
    const int sub = lane & 15;      // float4 slot within a 16-float4 chunk
    const bool hi4 = (lane & 4) != 0;
    const int row0 = blockIdx.x * 32 + wave * 8 + g * 2;

    const float4* xr0 = reinterpret_cast<const float4*>(x + (size_t)(row0 + 0) * D) + sub;
    const float4* xr1 = reinterpret_cast<const float4*>(x + (size_t)(row0 + 1) * D) + sub;
    const float4* gp  = reinterpret_cast<const float4*>(ws) + sub;   // protos_norm

    float acc[NPROTO][2];
    #pragma unroll
    for (int p = 0; p < NPROTO; ++p) { acc[p][0] = 0.f; acc[p][1] = 0.f; }
    float ssx[2] = {0.f, 0.f};

    float4 xa[2], xn[2];            // depth-1 ping-pong prefetch
    xa[0] = xr0[0]; xa[1] = xr1[0];

    #pragma unroll
    for (int j = 0; j < NCHUNK; ++j) {
        if (j + 1 < NCHUNK) {
            xn[0] = xr0[16 * (j + 1)];
            xn[1] = xr1[16 * (j + 1)];
        }
        const float4* pp = gp + 16 * j;
        #pragma unroll
        for (int p = 0; p < NPROTO; ++p) {
            const float4 pv = pp[p * D4];
            acc[p][0] += dot4f(xa[0], pv);
            acc[p][1] += dot4f(xa[1], pv);
        }
        ssx[0] += dot4f(xa[0], xa[0]);
        ssx[1] += dot4f(xa[1], xa[1]);
        if (j + 1 < NCHUNK) { xa[0] = xn[0]; xa[1] = xn[1]; }
    }

    #pragma unroll
    for (int r = 0; r < 2; ++r) {
        const float ss = red16(ssx[r], hi4);
        const float inv = 1.0f / fmaxf(sqrtf(ss), 1e-12f);

        // np-order scan in dist space (strict > keeps first index on ties)
        float best = 0.f; int bidx = 0;
        #pragma unroll
        for (int p = 0; p < NPROTO; ++p) {
            const float sim = red16(acc[p][r], hi4) * inv;
            const float u = expf(sim) / 10.0f;
            const float dcur = 1.0f / (1.0f + u);
            if (p == 0) best = dcur;
            else if (dcur > best) { best = dcur; bidx = p; }
        }

        const int row = row0 + r;
        if (sub == 0) out_min[row] = best;
        if (sub < NCLS)
            out_pred[(size_t)row * NCLS + sub] = ws[NPROTO * D + bidx * NCLS + sub];
    }
}

extern "C" void kernel_launch(void* const* d_in, const int* in_sizes, int n_in,
                              void* d_out, int out_size, void* d_ws, size_t ws_size,
                              hipStream_t stream) {
    const float* x          = (const float*)d_in[0];   // [B, 768]
    const int*   role_id    = (const int*)d_in[1];     // scalar
    const float* prototypes = (const float*)d_in[2];   // [260, 768]
    const float* W          = (const float*)d_in[3];   // [13, 768]
    const float* b          = (const float*)d_in[4];   // [13]
    float* out = (float*)d_out;
    float* ws  = (float*)d_ws;

    const int B = in_sizes[0] / D;                     // 131072

    proto_prep<<<NPROTO, 256, 0, stream>>>(prototypes, role_id, W, b, ws);
    proto_main<<<B / 32, 256, 0, stream>>>(x, ws, out, out + B);
}

// Round 11
// 227.168 us; speedup vs baseline: 10.4055x; 7.3776x over previous
//
#include <hip/hip_runtime.h>
#include <math.h>

#define D 768
#define NPROTO 20
#define NCLS 13
#define D4 (D / 4)      // 192 float4 per row
#define NCHUNK 12       // 16 lanes/row, one float4 each -> 12 chunks

__device__ __forceinline__ float dot4f(const float4 a, const float4 b) {
    return a.x * b.x + a.y * b.y + a.z * b.z + a.w * b.w;
}

template <int CTRL>
__device__ __forceinline__ float dpp_mov(float v) {
    return __int_as_float(__builtin_amdgcn_update_dpp(
        0, __float_as_int(v), CTRL, 0xF, 0xF, true));
}

// 16-lane butterfly, bit-identical pairing to __shfl_xor s=1,2,4,8,
// entirely on the VALU pipe (DPP). Verified on HW in rounds 8-10 (absmax 0.0).
// row_shr:N => lane i <- i-N ; row_shl:N => lane i <- i+N.
__device__ __forceinline__ float red16(float v, bool hi4) {
    v += dpp_mov<0xB1>(v);                 // quad_perm [1,0,3,2]  == xor 1
    v += dpp_mov<0x4E>(v);                 // quad_perm [2,3,0,1]  == xor 2
    const float up   = dpp_mov<0x114>(v);  // row_shr:4 : lane i <- i-4
    const float down = dpp_mov<0x104>(v);  // row_shl:4 : lane i <- i+4
    v += hi4 ? up : down;                  // exact partner lane^4
    v += dpp_mov<0x128>(v);                // row_ror:8 == xor 8 within 16
    return v;
}

// ws layout (floats): [0, 15360) protos_norm [20][768]; [15360, 15620) logits [20][13]

// One block per prototype. Numerics identical to rounds 1-10 (passed) prep.
__global__ __launch_bounds__(256) void proto_prep(
    const float* __restrict__ prototypes,
    const int* __restrict__ role_id,
    const float* __restrict__ W,
    const float* __restrict__ bvec,
    float* __restrict__ ws)
{
    const int p = blockIdx.x;            // 0..19
    const int tid = threadIdx.x;
    const int wave = tid >> 6;
    const int lane = tid & 63;

    const float4* src = reinterpret_cast<const float4*>(
        prototypes + ((size_t)role_id[0] * NPROTO + p) * D);
    float4 v[3];
    #pragma unroll
    for (int j = 0; j < 3; ++j) v[j] = src[lane + 64 * j];

    float ss = 0.f;
    #pragma unroll
    for (int j = 0; j < 3; ++j) ss += dot4f(v[j], v[j]);
    #pragma unroll
    for (int s = 1; s < 64; s <<= 1) ss += __shfl_xor(ss, s, 64);
    const float nrm = fmaxf(sqrtf(ss), 1e-12f);

    float4 nv[3];
    #pragma unroll
    for (int j = 0; j < 3; ++j) {
        nv[j].x = v[j].x / nrm; nv[j].y = v[j].y / nrm;
        nv[j].z = v[j].z / nrm; nv[j].w = v[j].w / nrm;
    }
    if (wave == 0) {
        float4* dst = reinterpret_cast<float4*>(ws + (size_t)p * D);
        #pragma unroll
        for (int j = 0; j < 3; ++j) dst[lane + 64 * j] = nv[j];
    }

    for (int r = wave; r < NCLS; r += 4) {
        const float4* wr = reinterpret_cast<const float4*>(W + (size_t)r * D);
        float a = 0.f;
        #pragma unroll
        for (int j = 0; j < 3; ++j) a += dot4f(nv[j], wr[lane + 64 * j]);
        #pragma unroll
        for (int s = 1; s < 64; s <<= 1) a += __shfl_xor(a, s, 64);
        if (lane == 0) ws[NPROTO * D + p * NCLS + r] = a + bvec[r];
    }
}

// Zero-LDS main kernel, ROLLED chunk loop. Protos read per-chunk from
// global ws (61 KB, L1/L2-resident, broadcast across the wave's 4 groups).
// 16 lanes/row, 2 rows/group -> 32 rows per 256-thr block, 4096 blocks.
// r10 lesson: a fully-unrolled chunk loop lets the scheduler hoist up to
// 240 global-load destinations -> spill even at 256 VGPRs. #pragma unroll 1
// bounds the live set to ~150 (20 in-flight proto loads + acc + prefetch).
__global__ __launch_bounds__(256, 1) void proto_main(
    const float* __restrict__ x,
    const float* __restrict__ ws,
    float* __restrict__ out_min,
    float* __restrict__ out_pred)
{
    const int tid = threadIdx.x;
    const int wave = tid >> 6;      // 0..3
    const int lane = tid & 63;
    const int g   = lane >> 4;      // group within wave (2 rows each)
    const int sub = lane & 15;      // float4 slot within a 16-float4 chunk
    const bool hi4 = (lane & 4) != 0;
    const int row0 = blockIdx.x * 32 + wave * 8 + g * 2;

    const float4* xr0 = reinterpret_cast<const float4*>(x + (size_t)(row0 + 0) * D) + sub;
    const float4* xr1 = reinterpret_cast<const float4*>(x + (size_t)(row0 + 1) * D) + sub;
    const float4* pp  = reinterpret_cast<const float4*>(ws) + sub;   // protos_norm

    float acc[NPROTO][2];
    #pragma unroll
    for (int p = 0; p < NPROTO; ++p) { acc[p][0] = 0.f; acc[p][1] = 0.f; }
    float ssx[2] = {0.f, 0.f};

    float4 xa0, xa1, xn0, xn1;      // depth-1 ping-pong prefetch
    xa0 = xr0[0]; xa1 = xr1[0];
    xr0 += 16; xr1 += 16;

    #pragma unroll 1
    for (int j = 0; j < NCHUNK; ++j) {
        if (j + 1 < NCHUNK) {       // prefetch next x chunk
            xn0 = xr0[0];
            xn1 = xr1[0];
            xr0 += 16; xr1 += 16;
        }
        #pragma unroll
        for (int p = 0; p < NPROTO; ++p) {
            const float4 pv = pp[p * D4];
            acc[p][0] += dot4f(xa0, pv);
            acc[p][1] += dot4f(xa1, pv);
        }
        ssx[0] += dot4f(xa0, xa0);
        ssx[1] += dot4f(xa1, xa1);
        pp += 16;
        xa0 = xn0; xa1 = xn1;
    }

    #pragma unroll
    for (int r = 0; r < 2; ++r) {
        const float ss = red16(r == 0 ? ssx[0] : ssx[1], hi4);
        const float inv = 1.0f / fmaxf(sqrtf(ss), 1e-12f);

        // np-order scan in dist space (strict > keeps first index on ties)
        float best = 0.f; int bidx = 0;
        #pragma unroll
        for (int p = 0; p < NPROTO; ++p) {
            const float sim = red16(acc[p][r], hi4) * inv;
            const float u = expf(sim) / 10.0f;
            const float dcur = 1.0f / (1.0f + u);
            if (p == 0) best = dcur;
            else if (dcur > best) { best = dcur; bidx = p; }
        }

        const int row = row0 + r;
        if (sub == 0) out_min[row] = best;
        if (sub < NCLS)
            out_pred[(size_t)row * NCLS + sub] = ws[NPROTO * D + bidx * NCLS + sub];
    }
}

extern "C" void kernel_launch(void* const* d_in, const int* in_sizes, int n_in,
                              void* d_out, int out_size, void* d_ws, size_t ws_size,
                              hipStream_t stream) {
    const float* x          = (const float*)d_in[0];   // [B, 768]
    const int*   role_id    = (const int*)d_in[1];     // scalar
    const float* prototypes = (const float*)d_in[2];   // [260, 768]
    const float* W          = (const float*)d_in[3];   // [13, 768]
    const float* b          = (const float*)d_in[4];   // [13]
    float* out = (float*)d_out;
    float* ws  = (float*)d_ws;

    const int B = in_sizes[0] / D;                     // 131072

    proto_prep<<<NPROTO, 256, 0, stream>>>(prototypes, role_id, W, b, ws);
    proto_main<<<B / 32, 256, 0, stream>>>(x, ws, out, out + B);
}